// Round 10
// baseline (753.758 us; speedup 1.0000x reference)
//
#include <hip/hip_runtime.h>

#define TT 128
#define BB 32
#define II 128
#define HH 320
#define OO 32
#define GG 8
#define HPAD 129   // s_hist row pitch (pad: rows are read down-column in final rewrite)

static __device__ __forceinline__ float fexp2(float x) { return __builtin_amdgcn_exp2f(x); }
static __device__ __forceinline__ float frcp(float x)  { return __builtin_amdgcn_rcpf(x); }

// tanh for x >= 0: 1 - 2/(e^{2x}+1), e^{2x} = exp2(x * 2*log2(e))
static __device__ __forceinline__ float tanh_pos(float x) {
    float e = fexp2(x * 2.8853900817779268f);
    return 1.0f - 2.0f * frcp(e + 1.0f);
}

// ---- DPP wave-64 sum reduce (VALU pipe) ----
template<int CTRL>
static __device__ __forceinline__ float dpp_add(float v) {
    int t = __builtin_amdgcn_update_dpp(0, __builtin_bit_cast(int, v),
                                        CTRL, 0xf, 0xf, true);
    return v + __builtin_bit_cast(float, t);
}
static __device__ __forceinline__ float bcast63(float v) {
    return __builtin_bit_cast(float,
        __builtin_amdgcn_readlane(__builtin_bit_cast(int, v), 63));
}
static __device__ __forceinline__ float wave_sum(float v) {
    v = dpp_add<0x111>(v);   // row_shr:1
    v = dpp_add<0x112>(v);   // row_shr:2
    v = dpp_add<0x114>(v);   // row_shr:4
    v = dpp_add<0x118>(v);   // row_shr:8
    v = dpp_add<0x142>(v);   // row_bcast:15
    v = dpp_add<0x143>(v);   // row_bcast:31
    return bcast63(v);
}

// L2-point atomics (no sc1 -> executed in the local XCD's L2; all 8 sibling
// blocks are handshake-verified to share that L2).
static __device__ __forceinline__ void l2_swap(float* p, float v) {
    asm volatile("global_atomic_swap %0, %1, off"
                 :: "v"(p), "v"(__builtin_bit_cast(unsigned, v)) : "memory");
}
static __device__ __forceinline__ float l2_read(const float* p) {
    unsigned u; unsigned z = 0u;
    asm volatile("global_atomic_add %0, %1, %2, off sc0\n\ts_waitcnt vmcnt(0)"
                 : "=v"(u) : "v"(p), "v"(z) : "memory");   // add 0, return old
    return __builtin_bit_cast(float, u);
}

__global__ __launch_bounds__(512, 2)
void leaky_rnn_kernel(const float* __restrict__ x, const float* __restrict__ Rs,
                      const float* __restrict__ Wx2h, const float* __restrict__ Wh2h,
                      const float* __restrict__ bh2h, const float* __restrict__ Wh2o,
                      const float* __restrict__ bh2o, const float* __restrict__ Wattn,
                      const float* __restrict__ battn, const float* __restrict__ cplas,
                      float* __restrict__ out, float* __restrict__ hs,
                      unsigned* __restrict__ ctr)
{
    const int tid  = threadIdx.x;
    const int bid  = blockIdx.x;
    // XCD-local sibling mapping (R1-verified: XCD = bid%8, so siblings of
    // batch b = {b, b+32, ...} all land on one XCD). Perf heuristic only --
    // the handshake below VERIFIES it before the fast path is used.
    const int b    = bid & 31;     // batch
    const int sub  = bid >> 5;     // 8 blocks per batch, 40 rows each
    const int w    = tid >> 6;     // wave 0..7
    const int lane = tid & 63;
    const int h0   = sub * 40;

    __shared__ float s_ea[GG * HH];      // masked relu(W_attn)
    __shared__ float s_out[2][HH];       // double-buffered prev-output (by t parity)
    __shared__ float s_logit[GG];
    __shared__ float s_hist[40 * HPAD];  // own 40 rows x 128 t; in-loop WRITTEN only,
                                         // READ only in the final phase after barriers.
    __shared__ float s_hs[16 * HH];      // readout staging
    __shared__ int   s_mode;             // 1 = all 8 siblings on one XCD
    __shared__ int   s_giveup;           // 1 = L2 fast poll failed once -> sticky agent

    unsigned* slots = ctr + 1024;        // handshake slots at ws+4KB, 128B apart

    // publish own XCC_ID via the proven agent path (overlaps with init below)
    if (tid == 0) {
        unsigned xid;
        asm volatile("s_getreg_b32 %0, hwreg(HW_REG_XCC_ID)" : "=s"(xid));
        __hip_atomic_store(&slots[(b * 8 + sub) * 32], xid + 1u,
                           __ATOMIC_RELAXED, __HIP_MEMORY_SCOPE_AGENT);
        s_giveup = 0;
    }

    // ---- one-time init ----
    for (int idx = tid; idx < GG * HH; idx += 512) {
        int h = idx % HH;
        float m = (h < 256) ? 1.f : (h == 256 ? -1.f : 0.f);  // mask_a (zc=63!)
        s_ea[idx] = fmaxf(Wattn[idx], 0.f) * m;
    }
    if (tid < HH) { s_out[0][tid] = 0.f; s_out[1][tid] = 0.f; }  // output0 = relu(0)

    // plastic weights in registers: 5 rows/wave, lane owns cols {lane, lane+64,...}
    float wx[5][2], wh[5][5], st[5], bh[5];
    int hrow[5];
#pragma unroll
    for (int r = 0; r < 5; ++r) {
        int h = h0 + w * 5 + r;
        hrow[r] = h;
        bh[r] = bh2h[h];
        st[r] = 0.f;
#pragma unroll
        for (int c = 0; c < 2; ++c)
            wx[r][c] = fmaxf(Wx2h[h * II + lane + 64 * c], 0.f);   // wx0 = relu(W_x2h)
#pragma unroll
        for (int c = 0; c < 5; ++c) {
            int j = lane + 64 * c;
            float v = fmaxf(Wh2h[h * HH + j], 0.f);
            v = (c == 4) ? -v : v;            // sign_h: j>=256 -> -1
            wh[r][c] = (j == h) ? 0.f : v;    // zero diagonal (1-eye)
        }
    }
    float batt = battn[w];  // wave w handles attn group g = w
    float c0 = fabsf(cplas[0]), c1 = fabsf(cplas[1]), c2 = fabsf(cplas[2]);
    float c3 = fabsf(cplas[3]), c4 = fabsf(cplas[4]), c5 = fabsf(cplas[5]);

    const float AX  = (float)(0.02 / 0.1);   // 0.2
    const float AW  = (float)(0.02 / 0.2);   // 0.1
    const float OMX = 1.f - AX;
    const float OMW = 1.f - AW;
    const float L2E = 1.4426950408889634f;

    // gather siblings' XCC_IDs; fast iff all 8 match (deterministic: every
    // sibling reads the same 8 agent-published values -> identical decision)
    if (tid == 0) {
        unsigned xid;
        asm volatile("s_getreg_b32 %0, hwreg(HW_REG_XCC_ID)" : "=s"(xid));
        unsigned tag = xid + 1u;
        int ok = 1;
        for (int s2 = 0; s2 < 8; ++s2) {
            unsigned v = 0u; int g2 = 0;
            do {
                v = __hip_atomic_load(&slots[(b * 8 + s2) * 32],
                                      __ATOMIC_RELAXED, __HIP_MEMORY_SCOPE_AGENT);
            } while (v == 0u && ++g2 < 2000000);
            if (v != tag) ok = 0;
        }
        s_mode = ok;
    }

    __syncthreads();
    const bool fast = (s_mode != 0);

    // prefetch x (both halves, per-thread regs) and Rs for t=0
    float xv0n = x[b * II + lane];
    float xv1n = x[b * II + lane + 64];
    float Rvn  = Rs[b];

#pragma unroll 1
    for (int t = 0; t < TT; ++t) {
        const float* so_cur = s_out[t & 1];
        float*       so_nxt = s_out[(t + 1) & 1];
        float xv0 = xv0n, xv1 = xv1n;
        float A   = AW * Rvn;

        // ---- attention logits: g = w, reduce over H (DPP, VALU pipe) ----
        float lp = 0.f;
#pragma unroll
        for (int k = 0; k < 5; ++k) {
            int hh2 = lane + 64 * k;
            lp = fmaf(s_ea[w * HH + hh2], so_cur[hh2], lp);
        }
        float lt = wave_sum(lp);
        if (lane == 0) s_logit[w] = lt + batt;
        __syncthreads();                                   // B1: s_logit visible

        // ---- redundant per-thread softmax ----
        float lg[8];
#pragma unroll
        for (int g = 0; g < 8; ++g) lg[g] = s_logit[g];
        float mx = lg[0];
#pragma unroll
        for (int g = 1; g < 8; ++g) mx = fmaxf(mx, lg[g]);
        float se = 0.f, eg[8];
#pragma unroll
        for (int g = 0; g < 8; ++g) { eg[g] = fexp2((lg[g] - mx) * L2E); se += eg[g]; }
        float rinv = frcp(se);
        float xmc0 = xv0 * eg[lane >> 4] * 8.f * rinv;
        float xmc1 = xv1 * eg[(lane >> 4) + 4] * 8.f * rinv;

        float oc[5];
#pragma unroll
        for (int c = 0; c < 5; ++c) oc[c] = so_cur[lane + 64 * c];

        // ---- 5 row-dot partials, 5-way ILP DPP reduce ----
        float p[5];
#pragma unroll
        for (int r = 0; r < 5; ++r) {
            int h = hrow[r];
            float pp = fmaxf(wx[r][0], 0.f) * xmc0;
            pp = fmaf(fmaxf(wx[r][1], 0.f), xmc1, pp);
#pragma unroll
            for (int c = 0; c < 5; ++c) {
                float wv = fmaxf(wh[r][c], 0.f);
                float so = (c == 4) ? -oc[4] : oc[c];        // sign_h fold
                float term = wv * so;
                term = ((lane + 64 * c) == h) ? 0.f : term;  // exclude diagonal
                pp += term;
            }
            p[r] = pp;
        }
#define DPP_L5(CTRL) { \
        p[0]=dpp_add<CTRL>(p[0]); p[1]=dpp_add<CTRL>(p[1]); \
        p[2]=dpp_add<CTRL>(p[2]); p[3]=dpp_add<CTRL>(p[3]); \
        p[4]=dpp_add<CTRL>(p[4]); }
        DPP_L5(0x111) DPP_L5(0x112) DPP_L5(0x114)
        DPP_L5(0x118) DPP_L5(0x142) DPP_L5(0x143)
#undef DPP_L5

        float no[5];
#pragma unroll
        for (int r = 0; r < 5; ++r) {
            float total = bcast63(p[r]) + bh[r];
            st[r] = fmaf(st[r], OMX, total * AX);
            no[r] = tanh_pos(fmaxf(st[r], 0.f));
        }

        // ---- batched publish (lanes 0..4, one line). Biased +2: poison /
        //      memset-0 are < 1. Fast mode DUAL-publishes: L2 swap first
        //      (low-latency for same-XCD consumers), agent store second
        //      (LLC safety net -> fallback polling always terminates).
        //      Publisher also writes so_nxt (LDS fast path, B2-ordered). ----
        {
            float pub = no[0];
            pub = (lane == 1) ? no[1] : pub;
            pub = (lane == 2) ? no[2] : pub;
            pub = (lane == 3) ? no[3] : pub;
            pub = (lane == 4) ? no[4] : pub;
            if (lane < 5) {
                float* dst = &hs[(t * BB + b) * HH + h0 + w * 5 + lane];
                float bp = pub + 2.0f;
                if (fast) l2_swap(dst, bp);
                __hip_atomic_store(dst, bp, __ATOMIC_RELAXED, __HIP_MEMORY_SCOPE_AGENT);
                s_hist[(w * 5 + lane) * HPAD + t] = pub;   // true value for final rewrite
                so_nxt[h0 + w * 5 + lane] = pub;           // own-row fast path (B2-ordered)
            }
        }

        // ---- plastic weight update (regs only; overlaps store propagation) ----
        if (t < TT - 1) {
            float Ac0 = A * c0, Ac1 = A * c1, Ac2 = A * c2;
            float Ac3 = A * c3, Ac4 = A * c4, Ac5 = A * c5;
#pragma unroll
            for (int r = 0; r < 5; ++r) {
                float u  = fmaf(Ac2, no[r], Ac0);
                float v  = Ac1 * no[r];
                float pp = fmaf(Ac5, no[r], Ac3);
                float qq = Ac4 * no[r];
                wx[r][0] = fmaf(wx[r][0], OMW, fmaf(u, xmc0, v));
                wx[r][1] = fmaf(wx[r][1], OMW, fmaf(u, xmc1, v));
#pragma unroll
                for (int c = 0; c < 5; ++c)
                    wh[r][c] = fmaf(wh[r][c], OMW, fmaf(pp, oc[c], qq));
            }
        }

        // prefetch next x/R while publish stores are in flight
        if (t + 1 < TT) {
            xv0n = x[((t + 1) * BB + b) * II + lane];
            xv1n = x[((t + 1) * BB + b) * II + lane + 64];
            Rvn  = Rs[(t + 1) * BB + b];
        }

        // ---- gather the 280 REMOTE rows (own 40 via so_nxt above; B2 orders).
        //      Fast: L2 atomic-add-0 poll (coherent point read, ~300cy RTT).
        //      Bounded guard -> sticky give-up -> proven agent 4-deep poll.
        //      Dual publish guarantees the agent path always sees the data. ----
        if (t < TT - 1 && tid < HH && !(tid >= h0 && tid < h0 + 40)) {
            const float* p2 = &hs[(t * BB + b) * HH + tid];
            float va = 0.f;
            if (fast && s_giveup == 0) {
                int guard = 0;
                do {
                    va = l2_read(p2);
                } while (va < 1.0f && ++guard < 3000);
                if (va < 1.0f) s_giveup = 1;   // benign race: worst case extra tries
            }
            if (va < 1.0f) {                   // slow path / safety net (R8 proven)
                float vb = __hip_atomic_load(p2, __ATOMIC_RELAXED, __HIP_MEMORY_SCOPE_AGENT);
                float vc = __hip_atomic_load(p2, __ATOMIC_RELAXED, __HIP_MEMORY_SCOPE_AGENT);
                float vd = __hip_atomic_load(p2, __ATOMIC_RELAXED, __HIP_MEMORY_SCOPE_AGENT);
                va = __hip_atomic_load(p2, __ATOMIC_RELAXED, __HIP_MEMORY_SCOPE_AGENT);
                float t0 = vb; vb = vc; vc = vd; vd = va; va = t0;
                int guard = 0;
                while (va < 1.0f && ++guard < 2000000) {
                    va = vb; vb = vc; vc = vd;
                    vd = __hip_atomic_load(p2, __ATOMIC_RELAXED, __HIP_MEMORY_SCOPE_AGENT);
                }
            }
            so_nxt[tid] = va - 2.0f;
        }
        __syncthreads();                                   // B2: so_nxt sealed
    }

    // ======== final phase ========
    // Barrier A among the 8 sibling blocks: everyone's t-loop done, all hs published.
    if (tid == 0) {
        __hip_atomic_fetch_add(&ctr[b * 32], 1u, __ATOMIC_RELAXED, __HIP_MEMORY_SCOPE_AGENT);
        int guard = 0;
        while (__hip_atomic_load(&ctr[b * 32], __ATOMIC_RELAXED, __HIP_MEMORY_SCOPE_AGENT) < 8u) {
            if (++guard > 2000000) break;
            __builtin_amdgcn_s_sleep(1);
        }
    }
    __syncthreads();

    // readout staging: load biased hs (LLC copy -- agent stores always ran),
    // subtract bias
    for (int idx = tid; idx < 16 * HH; idx += 512) {
        int tl = idx / HH, h = idx % HH;
        int t_g = sub * 16 + tl;
        s_hs[idx] = __hip_atomic_load(&hs[(t_g * BB + b) * HH + h],
                                      __ATOMIC_RELAXED, __HIP_MEMORY_SCOPE_AGENT) - 2.0f;
    }
    __syncthreads();
    {
        int t_loc = tid >> 5;          // 0..15
        int o     = tid & 31;
        int t_g   = sub * 16 + t_loc;
        const float* hp = &s_hs[t_loc * HH];
        float acc = bh2o[o];
#pragma unroll 4
        for (int h = 0; h < 257; ++h) {          // mask_o zero for h>256
            float m = (h == 256) ? -1.f : 1.f;   // h==256: sign -1, exist 1 (zc=63)
            acc = fmaf(fmaxf(Wh2o[o * HH + h], 0.f) * m, hp[h], acc);
        }
        float sg = frcp(1.f + fexp2(-acc * L2E));
        out[(t_g * BB + b) * OO + o] = sg;
    }

    // Barrier B: all siblings finished READING biased hs -> safe to rewrite
    __syncthreads();
    if (tid == 0) {
        __hip_atomic_fetch_add(&ctr[b * 32], 1u, __ATOMIC_RELAXED, __HIP_MEMORY_SCOPE_AGENT);
        int guard = 0;
        while (__hip_atomic_load(&ctr[b * 32], __ATOMIC_RELAXED, __HIP_MEMORY_SCOPE_AGENT) < 16u) {
            if (++guard > 2000000) break;
            __builtin_amdgcn_s_sleep(1);
        }
    }
    __syncthreads();

    // rewrite own rows of hs with TRUE values. Fast mode: ALSO swap the L2
    // copy, so the dirty L2 line holds the TRUE value -- the end-of-kernel
    // L2 writeback can then only write true data over the LLC copy.
    for (int idx = tid; idx < 40 * TT; idx += 512) {
        int row = idx >> 7;            // idx / 128
        int t   = idx & 127;
        float* dst = &hs[(t * BB + b) * HH + h0 + row];
        float tv = s_hist[row * HPAD + t];
        if (fast) l2_swap(dst, tv);
        __hip_atomic_store(dst, tv, __ATOMIC_RELAXED, __HIP_MEMORY_SCOPE_AGENT);
    }
}

extern "C" void kernel_launch(void* const* d_in, const int* in_sizes, int n_in,
                              void* d_out, int out_size, void* d_ws, size_t ws_size,
                              hipStream_t stream) {
    const float* x     = (const float*)d_in[0];
    const float* Rs    = (const float*)d_in[1];
    const float* Wx2h  = (const float*)d_in[2];
    const float* Wh2h  = (const float*)d_in[3];
    const float* bh2h  = (const float*)d_in[4];
    const float* Wh2o  = (const float*)d_in[5];
    const float* bh2o  = (const float*)d_in[6];
    const float* Wattn = (const float*)d_in[7];
    const float* battn = (const float*)d_in[8];
    const float* cplas = (const float*)d_in[9];
    float* out = (float*)d_out;
    float* hs  = out + TT * BB * OO;
    unsigned* ctr = (unsigned*)d_ws;   // [0,4KB): barrier ctrs; [4KB,36KB): XCD handshake

    hipMemsetAsync(d_ws, 0, 36864, stream);
    hipLaunchKernelGGL(leaky_rnn_kernel, dim3(256), dim3(512), 0, stream,
                       x, Rs, Wx2h, Wh2h, bh2h, Wh2o, bh2o, Wattn, battn, cplas,
                       out, hs, ctr);
}